// Round 1
// baseline (651.606 us; speedup 1.0000x reference)
//
#include <hip/hip_runtime.h>
#include <hip/hip_bf16.h>
#include <float.h>
#include <math.h>

// Problem constants (B, L, H, D fixed by the reference setup)
constexpr int B = 4;
constexpr int L = 2048;
constexpr int H = 16;
constexpr int D = 64;
constexpr int U = 40;   // u_top = min(5*ceil(ln(2048)), 2048) = 40

// ---------------------------------------------------------------------------
// Kernel 0: out = v  (identity copy in (B,L,H,D) layout), vectorized float4
// ---------------------------------------------------------------------------
__global__ void copy_v_kernel(const float* __restrict__ v, float* __restrict__ out, int n4) {
    int i = blockIdx.x * blockDim.x + threadIdx.x;
    int stride = gridDim.x * blockDim.x;
    const float4* src = reinterpret_cast<const float4*>(v);
    float4* dst = reinterpret_cast<float4*>(out);
    for (; i < n4; i += stride) dst[i] = src[i];
}

// ---------------------------------------------------------------------------
// Kernel 1: M[b,h,l] = max_s dot(q[b,l,h,:], k[b,sidx[l,s],h,:]) - sum_s/L
// One block per (b,l); thread t -> h = t/16, dg = t%16 (4 floats of D each).
// ---------------------------------------------------------------------------
__global__ void compute_M_kernel(const float* __restrict__ q, const float* __restrict__ k,
                                 const int* __restrict__ sidx, float* __restrict__ M, int SK) {
    int bl = blockIdx.x;
    int b = bl / L;
    int l = bl % L;
    int t = threadIdx.x;
    int h = t >> 4;
    int dg = t & 15;

    const float* qrow = q + ((size_t)(b * L + l)) * H * D + h * D + dg * 4;
    float4 qv = *reinterpret_cast<const float4*>(qrow);

    float mx = -FLT_MAX;
    float sm = 0.f;
    for (int s = 0; s < SK; ++s) {
        int kidx = sidx[l * SK + s];
        const float* krow = k + ((size_t)(b * L + kidx)) * H * D + h * D + dg * 4;
        float4 kv = *reinterpret_cast<const float4*>(krow);
        float p = qv.x * kv.x + qv.y * kv.y + qv.z * kv.z + qv.w * kv.w;
        // reduce across the 16 lanes sharing this h (lanes are contiguous in-wave)
        #pragma unroll
        for (int off = 8; off >= 1; off >>= 1) p += __shfl_xor(p, off, 16);
        mx = fmaxf(mx, p);
        sm += p;
    }
    if (dg == 0) {
        M[((size_t)(b * H + h)) * L + l] = mx - sm * (1.0f / (float)L);
    }
}

// ---------------------------------------------------------------------------
// Kernel 2: exact top-U selection per (b,h), replicating jax.lax.top_k
// tie-breaking (equal value -> lower index wins). 40 serial argmax passes.
// ---------------------------------------------------------------------------
__global__ void topk_kernel(const float* __restrict__ M, int* __restrict__ Mtop) {
    int bh = blockIdx.x;
    const float* m = M + (size_t)bh * L;
    __shared__ float vals[L];
    __shared__ float rv[4];
    __shared__ int ri[4];
    int t = threadIdx.x;

    for (int i = t; i < L; i += 256) vals[i] = m[i];
    __syncthreads();

    for (int u = 0; u < U; ++u) {
        float bv = -FLT_MAX;
        int bi = L;  // sentinel (worse than any real index at equal value)
        for (int i = t; i < L; i += 256) {
            float v = vals[i];
            if (v > bv || (v == bv && i < bi)) { bv = v; bi = i; }
        }
        #pragma unroll
        for (int off = 32; off >= 1; off >>= 1) {
            float ov = __shfl_xor(bv, off);
            int   oi = __shfl_xor(bi, off);
            if (ov > bv || (ov == bv && oi < bi)) { bv = ov; bi = oi; }
        }
        int w = t >> 6;
        if ((t & 63) == 0) { rv[w] = bv; ri[w] = bi; }
        __syncthreads();
        if (t == 0) {
            float fv = rv[0]; int fi = ri[0];
            #pragma unroll
            for (int j = 1; j < 4; ++j) {
                if (rv[j] > fv || (rv[j] == fv && ri[j] < fi)) { fv = rv[j]; fi = ri[j]; }
            }
            Mtop[bh * U + u] = fi;
            vals[fi] = -FLT_MAX;  // remove from further consideration
        }
        __syncthreads();
    }
}

// ---------------------------------------------------------------------------
// Kernel 3: dense attention for each selected query. One block per (b,h,u).
// scores = q_red . k / sqrt(D); softmax; ctx = attn @ v; write to out row.
// ---------------------------------------------------------------------------
__global__ void attn_kernel(const float* __restrict__ q, const float* __restrict__ k,
                            const float* __restrict__ v, const int* __restrict__ Mtop,
                            float* __restrict__ out) {
    int blk = blockIdx.x;
    int bh = blk / U;
    int u = blk % U;
    int b = bh / H;
    int h = bh % H;
    int qi = Mtop[bh * U + u];

    __shared__ float sc[L];        // scores -> probabilities
    __shared__ float qs[D];
    __shared__ float red[4];
    __shared__ float ctx_s[4][D];

    int t = threadIdx.x;
    if (t < D) qs[t] = q[((size_t)(b * L + qi)) * H * D + h * D + t];
    __syncthreads();

    // Phase 1: scores + local max
    float lm = -FLT_MAX;
    for (int i = t; i < L; i += 256) {
        const float* krow = k + ((size_t)(b * L + i)) * H * D + h * D;
        float acc = 0.f;
        #pragma unroll
        for (int d = 0; d < D; ++d) acc += qs[d] * krow[d];
        acc *= 0.125f;  // 1/sqrt(64)
        sc[i] = acc;
        lm = fmaxf(lm, acc);
    }
    #pragma unroll
    for (int off = 32; off >= 1; off >>= 1) lm = fmaxf(lm, __shfl_xor(lm, off));
    if ((t & 63) == 0) red[t >> 6] = lm;
    __syncthreads();
    float gm = fmaxf(fmaxf(red[0], red[1]), fmaxf(red[2], red[3]));

    // Phase 2: exponentiate + local sum
    float ls = 0.f;
    for (int i = t; i < L; i += 256) {
        float e = expf(sc[i] - gm);
        sc[i] = e;
        ls += e;
    }
    #pragma unroll
    for (int off = 32; off >= 1; off >>= 1) ls += __shfl_xor(ls, off);
    __syncthreads();  // everyone done reading red (gm) and writing sc
    if ((t & 63) == 0) red[t >> 6] = ls;
    __syncthreads();
    float inv = 1.0f / (red[0] + red[1] + red[2] + red[3]);

    // Phase 3: ctx[d] = sum_i p_i * v[b,i,h,d]; thread -> (d = t&63, group = t>>6)
    int d = t & 63;
    int g = t >> 6;
    float acc = 0.f;
    for (int i = g; i < L; i += 4) {
        acc += sc[i] * v[((size_t)(b * L + i)) * H * D + h * D + d];
    }
    ctx_s[g][d] = acc;
    __syncthreads();
    if (g == 0) {
        float c = (ctx_s[0][d] + ctx_s[1][d] + ctx_s[2][d] + ctx_s[3][d]) * inv;
        out[((size_t)(b * L + qi)) * H * D + h * D + d] = c;
    }
}

// ---------------------------------------------------------------------------
extern "C" void kernel_launch(void* const* d_in, const int* in_sizes, int n_in,
                              void* d_out, int out_size, void* d_ws, size_t ws_size,
                              hipStream_t stream) {
    const float* q = (const float*)d_in[0];
    const float* k = (const float*)d_in[1];
    const float* v = (const float*)d_in[2];
    const int* sidx = (const int*)d_in[3];
    float* out = (float*)d_out;

    int SK = in_sizes[3] / L;  // sample_k (40 for this shape)

    float* M = (float*)d_ws;                              // B*H*L floats
    int* Mtop = (int*)((char*)d_ws + (size_t)B * H * L * sizeof(float));  // B*H*U ints

    int n4 = (B * L * H * D) / 4;
    copy_v_kernel<<<2048, 256, 0, stream>>>(v, out, n4);
    compute_M_kernel<<<B * L, 256, 0, stream>>>(q, k, sidx, M, SK);
    topk_kernel<<<B * H, 256, 0, stream>>>(M, Mtop);
    attn_kernel<<<B * H * U, 256, 0, stream>>>(q, k, v, Mtop, out);
}

// Round 2
// 325.089 us; speedup vs baseline: 2.0044x; 2.0044x over previous
//
#include <hip/hip_runtime.h>
#include <hip/hip_bf16.h>
#include <float.h>
#include <math.h>

// Problem constants (B, L, H, D fixed by the reference setup)
constexpr int B = 4;
constexpr int L = 2048;
constexpr int H = 16;
constexpr int D = 64;
constexpr int U = 40;   // u_top = min(5*ceil(ln(2048)), 2048) = 40
constexpr int UG = 8;   // u's per pv block
constexpr int NCH = 8;  // L-chunks per (b,h) in scores kernel (256 rows each)

// ---------------------------------------------------------------------------
// Kernel 0: out = v  (identity copy in (B,L,H,D) layout), vectorized float4
// ---------------------------------------------------------------------------
__global__ void copy_v_kernel(const float* __restrict__ v, float* __restrict__ out, int n4) {
    int i = blockIdx.x * blockDim.x + threadIdx.x;
    int stride = gridDim.x * blockDim.x;
    const float4* src = reinterpret_cast<const float4*>(v);
    float4* dst = reinterpret_cast<float4*>(out);
    for (; i < n4; i += stride) dst[i] = src[i];
}

// ---------------------------------------------------------------------------
// Kernel 1: M[b,h,l] = max_s dot(q[b,l,h,:], k[b,sidx[l,s],h,:]) - sum_s/L
// One block per (b,l); thread t -> h = t/16, dg = t%16 (4 floats of D each).
// ---------------------------------------------------------------------------
__global__ void compute_M_kernel(const float* __restrict__ q, const float* __restrict__ k,
                                 const int* __restrict__ sidx, float* __restrict__ M, int SK) {
    int bl = blockIdx.x;
    int b = bl / L;
    int l = bl % L;
    int t = threadIdx.x;
    int h = t >> 4;
    int dg = t & 15;

    const float* qrow = q + ((size_t)(b * L + l)) * H * D + h * D + dg * 4;
    float4 qv = *reinterpret_cast<const float4*>(qrow);

    float mx = -FLT_MAX;
    float sm = 0.f;
    for (int s = 0; s < SK; ++s) {
        int kidx = sidx[l * SK + s];
        const float* krow = k + ((size_t)(b * L + kidx)) * H * D + h * D + dg * 4;
        float4 kv = *reinterpret_cast<const float4*>(krow);
        float p = qv.x * kv.x + qv.y * kv.y + qv.z * kv.z + qv.w * kv.w;
        #pragma unroll
        for (int off = 8; off >= 1; off >>= 1) p += __shfl_xor(p, off, 16);
        mx = fmaxf(mx, p);
        sm += p;
    }
    if (dg == 0) {
        M[((size_t)(b * H + h)) * L + l] = mx - sm * (1.0f / (float)L);
    }
}

// ---------------------------------------------------------------------------
// Kernel 2: exact top-U selection per (b,h), replicating jax.lax.top_k
// tie-breaking (equal value -> lower index wins). 40 serial argmax passes.
// ---------------------------------------------------------------------------
__global__ void topk_kernel(const float* __restrict__ M, int* __restrict__ Mtop) {
    int bh = blockIdx.x;
    const float* m = M + (size_t)bh * L;
    __shared__ float vals[L];
    __shared__ float rv[4];
    __shared__ int ri[4];
    int t = threadIdx.x;

    for (int i = t; i < L; i += 256) vals[i] = m[i];
    __syncthreads();

    for (int u = 0; u < U; ++u) {
        float bv = -FLT_MAX;
        int bi = L;
        for (int i = t; i < L; i += 256) {
            float v = vals[i];
            if (v > bv || (v == bv && i < bi)) { bv = v; bi = i; }
        }
        #pragma unroll
        for (int off = 32; off >= 1; off >>= 1) {
            float ov = __shfl_xor(bv, off);
            int   oi = __shfl_xor(bi, off);
            if (ov > bv || (ov == bv && oi < bi)) { bv = ov; bi = oi; }
        }
        int w = t >> 6;
        if ((t & 63) == 0) { rv[w] = bv; ri[w] = bi; }
        __syncthreads();
        if (t == 0) {
            float fv = rv[0]; int fi = ri[0];
            #pragma unroll
            for (int j = 1; j < 4; ++j) {
                if (rv[j] > fv || (rv[j] == fv && ri[j] < fi)) { fv = rv[j]; fi = ri[j]; }
            }
            Mtop[bh * U + u] = fi;
            vals[fi] = -FLT_MAX;
        }
        __syncthreads();
    }
}

// ---------------------------------------------------------------------------
// Kernel 3a: scores. Block = (bh, L-chunk of 256). One thread per key row.
// k row in 16 float4 regs; q rows (all 40) staged in LDS, broadcast reads.
// Writes sc[bh][u][r] = (q_u . k_r) / 8, coalesced over r.
// ---------------------------------------------------------------------------
__global__ void scores_kernel(const float* __restrict__ q, const float* __restrict__ k,
                              const int* __restrict__ Mtop, float* __restrict__ sc) {
    int blk = blockIdx.x;
    int bh = blk >> 3;           // /NCH
    int ch = blk & (NCH - 1);
    int b = bh / H, h = bh % H;
    int t = threadIdx.x;

    __shared__ __align__(16) float qs[U][D];
    for (int i = t; i < U * D; i += 256) {
        int u = i >> 6, dd = i & 63;
        int qi = Mtop[bh * U + u];
        qs[u][dd] = q[((size_t)(b * L + qi)) * H * D + h * D + dd];
    }
    __syncthreads();

    int r = ch * 256 + t;
    const float4* krow = reinterpret_cast<const float4*>(k + ((size_t)(b * L + r)) * H * D + h * D);
    float4 kr[16];
    #pragma unroll
    for (int j = 0; j < 16; ++j) kr[j] = krow[j];

    float* scb = sc + (size_t)bh * U * L;
    for (int u = 0; u < U; ++u) {
        const float4* qrow = reinterpret_cast<const float4*>(qs[u]);
        float acc = 0.f;
        #pragma unroll
        for (int j = 0; j < 16; ++j) {
            float4 qv = qrow[j];
            acc += qv.x * kr[j].x + qv.y * kr[j].y + qv.z * kr[j].z + qv.w * kr[j].w;
        }
        scb[(size_t)u * L + r] = acc * 0.125f;
    }
}

// ---------------------------------------------------------------------------
// Kernel 3b: softmax over each sc row of L. Block per (bh,u). 8 vals/thread.
// In-place: sc row becomes probabilities.
// ---------------------------------------------------------------------------
__global__ void softmax_kernel(float* __restrict__ sc) {
    int bhu = blockIdx.x;
    float* s = sc + (size_t)bhu * L;
    int t = threadIdx.x;
    __shared__ float redm[4];
    __shared__ float reds[4];

    float4 a = reinterpret_cast<const float4*>(s)[t];
    float4 c = reinterpret_cast<const float4*>(s)[t + 256];

    float m = fmaxf(fmaxf(fmaxf(a.x, a.y), fmaxf(a.z, a.w)),
                    fmaxf(fmaxf(c.x, c.y), fmaxf(c.z, c.w)));
    #pragma unroll
    for (int off = 32; off >= 1; off >>= 1) m = fmaxf(m, __shfl_xor(m, off));
    if ((t & 63) == 0) redm[t >> 6] = m;
    __syncthreads();
    float gm = fmaxf(fmaxf(redm[0], redm[1]), fmaxf(redm[2], redm[3]));

    a.x = __expf(a.x - gm); a.y = __expf(a.y - gm);
    a.z = __expf(a.z - gm); a.w = __expf(a.w - gm);
    c.x = __expf(c.x - gm); c.y = __expf(c.y - gm);
    c.z = __expf(c.z - gm); c.w = __expf(c.w - gm);
    float ls = a.x + a.y + a.z + a.w + c.x + c.y + c.z + c.w;
    #pragma unroll
    for (int off = 32; off >= 1; off >>= 1) ls += __shfl_xor(ls, off);
    if ((t & 63) == 0) reds[t >> 6] = ls;
    __syncthreads();
    float inv = 1.0f / (reds[0] + reds[1] + reds[2] + reds[3]);

    a.x *= inv; a.y *= inv; a.z *= inv; a.w *= inv;
    c.x *= inv; c.y *= inv; c.z *= inv; c.w *= inv;
    reinterpret_cast<float4*>(s)[t] = a;
    reinterpret_cast<float4*>(s)[t + 256] = c;
}

// ---------------------------------------------------------------------------
// Kernel 3c: PV. Block per (bh, u-group of 8). Wave w covers rows w*512..+511.
// v reads coalesced (lane=d); p reads wave-uniform (single line). LDS reduce.
// ---------------------------------------------------------------------------
__global__ void pv_kernel(const float* __restrict__ v, const float* __restrict__ p,
                          const int* __restrict__ Mtop, float* __restrict__ out) {
    int blk = blockIdx.x;
    int bh = blk / (U / UG);
    int ug = blk % (U / UG);
    int b = bh / H, h = bh % H;
    int t = threadIdx.x;
    int d = t & 63;
    int w = t >> 6;

    const float* pb = p + ((size_t)bh * U + (size_t)ug * UG) * L;
    float acc[UG];
    #pragma unroll
    for (int u = 0; u < UG; ++u) acc[u] = 0.f;

    for (int r = w * 512; r < (w + 1) * 512; ++r) {
        float vv = v[((size_t)(b * L + r)) * H * D + h * D + d];
        #pragma unroll
        for (int u = 0; u < UG; ++u) acc[u] += pb[(size_t)u * L + r] * vv;
    }

    __shared__ float red[4][UG][64];
    #pragma unroll
    for (int u = 0; u < UG; ++u) red[w][u][d] = acc[u];
    __syncthreads();

    for (int i = t; i < UG * 64; i += 256) {
        int u = i >> 6, dd = i & 63;
        float s = red[0][u][dd] + red[1][u][dd] + red[2][u][dd] + red[3][u][dd];
        int qi = Mtop[bh * U + ug * UG + u];
        out[((size_t)(b * L + qi)) * H * D + h * D + dd] = s;
    }
}

// ---------------------------------------------------------------------------
// Fallback attention (round-1 version) if workspace too small for score buf.
// ---------------------------------------------------------------------------
__global__ void attn_kernel_fallback(const float* __restrict__ q, const float* __restrict__ k,
                                     const float* __restrict__ v, const int* __restrict__ Mtop,
                                     float* __restrict__ out) {
    int blk = blockIdx.x;
    int bh = blk / U;
    int u = blk % U;
    int b = bh / H;
    int h = bh % H;
    int qi = Mtop[bh * U + u];

    __shared__ float sc[L];
    __shared__ float qs[D];
    __shared__ float red[4];
    __shared__ float ctx_s[4][D];

    int t = threadIdx.x;
    if (t < D) qs[t] = q[((size_t)(b * L + qi)) * H * D + h * D + t];
    __syncthreads();

    float lm = -FLT_MAX;
    for (int i = t; i < L; i += 256) {
        const float* krow = k + ((size_t)(b * L + i)) * H * D + h * D;
        float acc = 0.f;
        #pragma unroll
        for (int dd = 0; dd < D; ++dd) acc += qs[dd] * krow[dd];
        acc *= 0.125f;
        sc[i] = acc;
        lm = fmaxf(lm, acc);
    }
    #pragma unroll
    for (int off = 32; off >= 1; off >>= 1) lm = fmaxf(lm, __shfl_xor(lm, off));
    if ((t & 63) == 0) red[t >> 6] = lm;
    __syncthreads();
    float gm = fmaxf(fmaxf(red[0], red[1]), fmaxf(red[2], red[3]));

    float ls = 0.f;
    for (int i = t; i < L; i += 256) {
        float e = expf(sc[i] - gm);
        sc[i] = e;
        ls += e;
    }
    #pragma unroll
    for (int off = 32; off >= 1; off >>= 1) ls += __shfl_xor(ls, off);
    __syncthreads();
    if ((t & 63) == 0) red[t >> 6] = ls;
    __syncthreads();
    float inv = 1.0f / (red[0] + red[1] + red[2] + red[3]);

    int d = t & 63;
    int g = t >> 6;
    float acc = 0.f;
    for (int i = g; i < L; i += 4) {
        acc += sc[i] * v[((size_t)(b * L + i)) * H * D + h * D + d];
    }
    ctx_s[g][d] = acc;
    __syncthreads();
    if (g == 0) {
        float c = (ctx_s[0][d] + ctx_s[1][d] + ctx_s[2][d] + ctx_s[3][d]) * inv;
        out[((size_t)(b * L + qi)) * H * D + h * D + d] = c;
    }
}

// ---------------------------------------------------------------------------
extern "C" void kernel_launch(void* const* d_in, const int* in_sizes, int n_in,
                              void* d_out, int out_size, void* d_ws, size_t ws_size,
                              hipStream_t stream) {
    const float* q = (const float*)d_in[0];
    const float* k = (const float*)d_in[1];
    const float* v = (const float*)d_in[2];
    const int* sidx = (const int*)d_in[3];
    float* out = (float*)d_out;

    int SK = in_sizes[3] / L;  // sample_k (40 for this shape)

    // Workspace layout
    size_t offM = 0;                                        // B*H*L floats
    size_t offMtop = offM + (size_t)B * H * L * sizeof(float);
    size_t offSc = offMtop + (size_t)B * H * U * sizeof(int);
    offSc = (offSc + 255) & ~(size_t)255;                   // align
    size_t needed = offSc + (size_t)B * H * U * L * sizeof(float);

    float* M = (float*)((char*)d_ws + offM);
    int* Mtop = (int*)((char*)d_ws + offMtop);
    float* sc = (float*)((char*)d_ws + offSc);

    int n4 = (B * L * H * D) / 4;
    copy_v_kernel<<<2048, 256, 0, stream>>>(v, out, n4);
    compute_M_kernel<<<B * L, 256, 0, stream>>>(q, k, sidx, M, SK);
    topk_kernel<<<B * H, 256, 0, stream>>>(M, Mtop);

    if (ws_size >= needed) {
        scores_kernel<<<B * H * NCH, 256, 0, stream>>>(q, k, Mtop, sc);
        softmax_kernel<<<B * H * U, 256, 0, stream>>>(sc);
        pv_kernel<<<B * H * (U / UG), 256, 0, stream>>>(v, sc, Mtop, out);
    } else {
        attn_kernel_fallback<<<B * H * U, 256, 0, stream>>>(q, k, v, Mtop, out);
    }
}

// Round 3
// 300.965 us; speedup vs baseline: 2.1651x; 1.0802x over previous
//
#include <hip/hip_runtime.h>
#include <hip/hip_bf16.h>
#include <float.h>
#include <math.h>

// Problem constants (B, L, H, D fixed by the reference setup)
constexpr int B = 4;
constexpr int L = 2048;
constexpr int H = 16;
constexpr int D = 64;
constexpr int U = 40;   // u_top = min(5*ceil(ln(2048)), 2048) = 40
constexpr int UG = 8;   // u's per pv block
constexpr int NCH = 8;  // L-chunks per (b,h) in scores kernel (256 rows each)
constexpr int LPB = 16; // l's per block in compute_M v2

typedef float floatx4 __attribute__((ext_vector_type(4)));

// ---------------------------------------------------------------------------
// Kernel 0: out = v  (identity copy), nontemporal both ways (out never re-read,
// keep L2 clean for the gather kernels).
// ---------------------------------------------------------------------------
__global__ void copy_v_kernel(const float* __restrict__ v, float* __restrict__ out, int n4) {
    int i = blockIdx.x * blockDim.x + threadIdx.x;
    int stride = gridDim.x * blockDim.x;
    const floatx4* src = reinterpret_cast<const floatx4*>(v);
    floatx4* dst = reinterpret_cast<floatx4*>(out);
    for (; i < n4; i += stride) {
        floatx4 x = __builtin_nontemporal_load(src + i);
        __builtin_nontemporal_store(x, dst + i);
    }
}

// ---------------------------------------------------------------------------
// Kernel 1 v2: M[b,h,l] over 16 l's per block, partitioned by (b,h) with
// XCD-affinity swizzle so each XCD's L2 holds only 8 bh k-slices (4.2 MB of
// touched 128B lines). 16-lane group per l: 256 B k segment, shfl reduce.
// ---------------------------------------------------------------------------
template<int SKC>
__global__ void compute_M_kernel2(const float* __restrict__ q, const float* __restrict__ k,
                                  const int* __restrict__ sidx, float* __restrict__ M) {
    int blk = blockIdx.x;
    // swizzle: all blocks of a given bh land on XCD bh%8 (empirical round-robin)
    int xcd = blk & 7;
    int rest = blk >> 3;
    int bh_hi = rest & 7;
    int chunk = rest >> 3;            // 0 .. L/LPB-1
    int bh = bh_hi * 8 + xcd;         // 0..63, bh%8 == blk%8
    int b = bh >> 4, h = bh & 15;

    int t = threadIdx.x;
    int lg = t >> 4;                  // local l 0..15
    int dg = t & 15;                  // 4-float group of D

    __shared__ int s_idx[LPB * SKC];
    for (int i = t; i < LPB * SKC; i += 256)
        s_idx[i] = sidx[(size_t)(chunk * LPB) * SKC + i];
    __syncthreads();

    int l = chunk * LPB + lg;
    floatx4 qv = __builtin_nontemporal_load(
        reinterpret_cast<const floatx4*>(q + ((size_t)(b * L + l) * H + h) * D + dg * 4));

    float mx = -FLT_MAX;
    float sm = 0.f;
    #pragma unroll 4
    for (int s = 0; s < SKC; ++s) {
        int kidx = s_idx[lg * SKC + s];
        floatx4 kv = *reinterpret_cast<const floatx4*>(
            k + ((size_t)(b * L + kidx) * H + h) * D + dg * 4);
        float p = qv.x * kv.x + qv.y * kv.y + qv.z * kv.z + qv.w * kv.w;
        #pragma unroll
        for (int off = 8; off >= 1; off >>= 1) p += __shfl_xor(p, off, 16);
        mx = fmaxf(mx, p);
        sm += p;
    }
    if (dg == 0) {
        M[(size_t)bh * L + l] = mx - sm * (1.0f / (float)L);
    }
}

// Fallback (round-2 version) for unexpected SK
__global__ void compute_M_kernel(const float* __restrict__ q, const float* __restrict__ k,
                                 const int* __restrict__ sidx, float* __restrict__ M, int SK) {
    int bl = blockIdx.x;
    int b = bl / L;
    int l = bl % L;
    int t = threadIdx.x;
    int h = t >> 4;
    int dg = t & 15;

    const float* qrow = q + ((size_t)(b * L + l)) * H * D + h * D + dg * 4;
    float4 qv = *reinterpret_cast<const float4*>(qrow);

    float mx = -FLT_MAX;
    float sm = 0.f;
    for (int s = 0; s < SK; ++s) {
        int kidx = sidx[l * SK + s];
        const float* krow = k + ((size_t)(b * L + kidx)) * H * D + h * D + dg * 4;
        float4 kv = *reinterpret_cast<const float4*>(krow);
        float p = qv.x * kv.x + qv.y * kv.y + qv.z * kv.z + qv.w * kv.w;
        #pragma unroll
        for (int off = 8; off >= 1; off >>= 1) p += __shfl_xor(p, off, 16);
        mx = fmaxf(mx, p);
        sm += p;
    }
    if (dg == 0) {
        M[((size_t)(b * H + h)) * L + l] = mx - sm * (1.0f / (float)L);
    }
}

// ---------------------------------------------------------------------------
// Kernel 2: exact top-U selection per (b,h), replicating jax.lax.top_k
// tie-breaking (equal value -> lower index wins). 40 serial argmax passes.
// ---------------------------------------------------------------------------
__global__ void topk_kernel(const float* __restrict__ M, int* __restrict__ Mtop) {
    int bh = blockIdx.x;
    const float* m = M + (size_t)bh * L;
    __shared__ float vals[L];
    __shared__ float rv[4];
    __shared__ int ri[4];
    int t = threadIdx.x;

    for (int i = t; i < L; i += 256) vals[i] = m[i];
    __syncthreads();

    for (int u = 0; u < U; ++u) {
        float bv = -FLT_MAX;
        int bi = L;
        for (int i = t; i < L; i += 256) {
            float v = vals[i];
            if (v > bv || (v == bv && i < bi)) { bv = v; bi = i; }
        }
        #pragma unroll
        for (int off = 32; off >= 1; off >>= 1) {
            float ov = __shfl_xor(bv, off);
            int   oi = __shfl_xor(bi, off);
            if (ov > bv || (ov == bv && oi < bi)) { bv = ov; bi = oi; }
        }
        int w = t >> 6;
        if ((t & 63) == 0) { rv[w] = bv; ri[w] = bi; }
        __syncthreads();
        if (t == 0) {
            float fv = rv[0]; int fi = ri[0];
            #pragma unroll
            for (int j = 1; j < 4; ++j) {
                if (rv[j] > fv || (rv[j] == fv && ri[j] < fi)) { fv = rv[j]; fi = ri[j]; }
            }
            Mtop[bh * U + u] = fi;
            vals[fi] = -FLT_MAX;
        }
        __syncthreads();
    }
}

// ---------------------------------------------------------------------------
// Kernel 3a: scores. Block = (bh, L-chunk of 256). One thread per key row.
// ---------------------------------------------------------------------------
__global__ void scores_kernel(const float* __restrict__ q, const float* __restrict__ k,
                              const int* __restrict__ Mtop, float* __restrict__ sc) {
    int blk = blockIdx.x;
    int bh = blk >> 3;           // /NCH
    int ch = blk & (NCH - 1);
    int b = bh / H, h = bh % H;
    int t = threadIdx.x;

    __shared__ __align__(16) float qs[U][D];
    for (int i = t; i < U * D; i += 256) {
        int u = i >> 6, dd = i & 63;
        int qi = Mtop[bh * U + u];
        qs[u][dd] = q[((size_t)(b * L + qi)) * H * D + h * D + dd];
    }
    __syncthreads();

    int r = ch * 256 + t;
    const float4* krow = reinterpret_cast<const float4*>(k + ((size_t)(b * L + r)) * H * D + h * D);
    float4 kr[16];
    #pragma unroll
    for (int j = 0; j < 16; ++j) kr[j] = krow[j];

    float* scb = sc + (size_t)bh * U * L;
    for (int u = 0; u < U; ++u) {
        const float4* qrow = reinterpret_cast<const float4*>(qs[u]);
        float acc = 0.f;
        #pragma unroll
        for (int j = 0; j < 16; ++j) {
            float4 qv = qrow[j];
            acc += qv.x * kr[j].x + qv.y * kr[j].y + qv.z * kr[j].z + qv.w * kr[j].w;
        }
        scb[(size_t)u * L + r] = acc * 0.125f;
    }
}

// ---------------------------------------------------------------------------
// Kernel 3b: softmax over each sc row of L. Block per (bh,u). 8 vals/thread.
// ---------------------------------------------------------------------------
__global__ void softmax_kernel(float* __restrict__ sc) {
    int bhu = blockIdx.x;
    float* s = sc + (size_t)bhu * L;
    int t = threadIdx.x;
    __shared__ float redm[4];
    __shared__ float reds[4];

    float4 a = reinterpret_cast<const float4*>(s)[t];
    float4 c = reinterpret_cast<const float4*>(s)[t + 256];

    float m = fmaxf(fmaxf(fmaxf(a.x, a.y), fmaxf(a.z, a.w)),
                    fmaxf(fmaxf(c.x, c.y), fmaxf(c.z, c.w)));
    #pragma unroll
    for (int off = 32; off >= 1; off >>= 1) m = fmaxf(m, __shfl_xor(m, off));
    if ((t & 63) == 0) redm[t >> 6] = m;
    __syncthreads();
    float gm = fmaxf(fmaxf(redm[0], redm[1]), fmaxf(redm[2], redm[3]));

    a.x = __expf(a.x - gm); a.y = __expf(a.y - gm);
    a.z = __expf(a.z - gm); a.w = __expf(a.w - gm);
    c.x = __expf(c.x - gm); c.y = __expf(c.y - gm);
    c.z = __expf(c.z - gm); c.w = __expf(c.w - gm);
    float ls = a.x + a.y + a.z + a.w + c.x + c.y + c.z + c.w;
    #pragma unroll
    for (int off = 32; off >= 1; off >>= 1) ls += __shfl_xor(ls, off);
    if ((t & 63) == 0) reds[t >> 6] = ls;
    __syncthreads();
    float inv = 1.0f / (reds[0] + reds[1] + reds[2] + reds[3]);

    a.x *= inv; a.y *= inv; a.z *= inv; a.w *= inv;
    c.x *= inv; c.y *= inv; c.z *= inv; c.w *= inv;
    reinterpret_cast<float4*>(s)[t] = a;
    reinterpret_cast<float4*>(s)[t + 256] = c;
}

// ---------------------------------------------------------------------------
// Kernel 3c: PV. Block per (bh, u-group of 8), XCD-affinity swizzled so v
// slices stay resident per-XCD. Wave w covers rows w*512..+511.
// ---------------------------------------------------------------------------
__global__ void pv_kernel(const float* __restrict__ v, const float* __restrict__ p,
                          const int* __restrict__ Mtop, float* __restrict__ out) {
    int blk = blockIdx.x;
    // swizzle: bh%8 == blk%8
    int xcd = blk & 7;
    int rest = blk >> 3;          // 0..39
    int bh_hi = rest & 7;
    int ug = rest >> 3;           // 0..4
    int bh = bh_hi * 8 + xcd;
    int b = bh / H, h = bh % H;
    int t = threadIdx.x;
    int d = t & 63;
    int w = t >> 6;

    const float* pb = p + ((size_t)bh * U + (size_t)ug * UG) * L;
    float acc[UG];
    #pragma unroll
    for (int u = 0; u < UG; ++u) acc[u] = 0.f;

    for (int r = w * 512; r < (w + 1) * 512; ++r) {
        float vv = v[((size_t)(b * L + r)) * H * D + h * D + d];
        #pragma unroll
        for (int u = 0; u < UG; ++u) acc[u] += pb[(size_t)u * L + r] * vv;
    }

    __shared__ float red[4][UG][64];
    #pragma unroll
    for (int u = 0; u < UG; ++u) red[w][u][d] = acc[u];
    __syncthreads();

    for (int i = t; i < UG * 64; i += 256) {
        int u = i >> 6, dd = i & 63;
        float s = red[0][u][dd] + red[1][u][dd] + red[2][u][dd] + red[3][u][dd];
        int qi = Mtop[bh * U + ug * UG + u];
        out[((size_t)(b * L + qi)) * H * D + h * D + dd] = s;
    }
}

// ---------------------------------------------------------------------------
// Fallback attention if workspace too small for the score buffer.
// ---------------------------------------------------------------------------
__global__ void attn_kernel_fallback(const float* __restrict__ q, const float* __restrict__ k,
                                     const float* __restrict__ v, const int* __restrict__ Mtop,
                                     float* __restrict__ out) {
    int blk = blockIdx.x;
    int bh = blk / U;
    int u = blk % U;
    int b = bh / H;
    int h = bh % H;
    int qi = Mtop[bh * U + u];

    __shared__ float sc[L];
    __shared__ float qs[D];
    __shared__ float red[4];
    __shared__ float ctx_s[4][D];

    int t = threadIdx.x;
    if (t < D) qs[t] = q[((size_t)(b * L + qi)) * H * D + h * D + t];
    __syncthreads();

    float lm = -FLT_MAX;
    for (int i = t; i < L; i += 256) {
        const float* krow = k + ((size_t)(b * L + i)) * H * D + h * D;
        float acc = 0.f;
        #pragma unroll
        for (int dd = 0; dd < D; ++dd) acc += qs[dd] * krow[dd];
        acc *= 0.125f;
        sc[i] = acc;
        lm = fmaxf(lm, acc);
    }
    #pragma unroll
    for (int off = 32; off >= 1; off >>= 1) lm = fmaxf(lm, __shfl_xor(lm, off));
    if ((t & 63) == 0) red[t >> 6] = lm;
    __syncthreads();
    float gm = fmaxf(fmaxf(red[0], red[1]), fmaxf(red[2], red[3]));

    float ls = 0.f;
    for (int i = t; i < L; i += 256) {
        float e = expf(sc[i] - gm);
        sc[i] = e;
        ls += e;
    }
    #pragma unroll
    for (int off = 32; off >= 1; off >>= 1) ls += __shfl_xor(ls, off);
    __syncthreads();
    if ((t & 63) == 0) red[t >> 6] = ls;
    __syncthreads();
    float inv = 1.0f / (red[0] + red[1] + red[2] + red[3]);

    int d = t & 63;
    int g = t >> 6;
    float acc = 0.f;
    for (int i = g; i < L; i += 4) {
        acc += sc[i] * v[((size_t)(b * L + i)) * H * D + h * D + d];
    }
    ctx_s[g][d] = acc;
    __syncthreads();
    if (g == 0) {
        float c = (ctx_s[0][d] + ctx_s[1][d] + ctx_s[2][d] + ctx_s[3][d]) * inv;
        out[((size_t)(b * L + qi)) * H * D + h * D + d] = c;
    }
}

// ---------------------------------------------------------------------------
extern "C" void kernel_launch(void* const* d_in, const int* in_sizes, int n_in,
                              void* d_out, int out_size, void* d_ws, size_t ws_size,
                              hipStream_t stream) {
    const float* q = (const float*)d_in[0];
    const float* k = (const float*)d_in[1];
    const float* v = (const float*)d_in[2];
    const int* sidx = (const int*)d_in[3];
    float* out = (float*)d_out;

    int SK = in_sizes[3] / L;  // sample_k (40 for this shape)

    // Workspace layout
    size_t offM = 0;                                        // B*H*L floats
    size_t offMtop = offM + (size_t)B * H * L * sizeof(float);
    size_t offSc = offMtop + (size_t)B * H * U * sizeof(int);
    offSc = (offSc + 255) & ~(size_t)255;                   // align
    size_t needed = offSc + (size_t)B * H * U * L * sizeof(float);

    float* M = (float*)((char*)d_ws + offM);
    int* Mtop = (int*)((char*)d_ws + offMtop);
    float* sc = (float*)((char*)d_ws + offSc);

    int n4 = (B * L * H * D) / 4;
    copy_v_kernel<<<2048, 256, 0, stream>>>(v, out, n4);

    if (SK == 40) {
        compute_M_kernel2<40><<<B * H * (L / LPB), 256, 0, stream>>>(q, k, sidx, M);
    } else {
        compute_M_kernel<<<B * L, 256, 0, stream>>>(q, k, sidx, M, SK);
    }
    topk_kernel<<<B * H, 256, 0, stream>>>(M, Mtop);

    if (ws_size >= needed) {
        scores_kernel<<<B * H * NCH, 256, 0, stream>>>(q, k, Mtop, sc);
        softmax_kernel<<<B * H * U, 256, 0, stream>>>(sc);
        pv_kernel<<<B * H * (U / UG), 256, 0, stream>>>(v, sc, Mtop, out);
    } else {
        attn_kernel_fallback<<<B * H * U, 256, 0, stream>>>(q, k, v, Mtop, out);
    }
}

// Round 4
// 276.467 us; speedup vs baseline: 2.3569x; 1.0886x over previous
//
#include <hip/hip_runtime.h>
#include <hip/hip_bf16.h>
#include <float.h>
#include <math.h>

// Problem constants (B, L, H, D fixed by the reference setup)
constexpr int B = 4;
constexpr int L = 2048;
constexpr int H = 16;
constexpr int D = 64;
constexpr int U = 40;   // u_top = min(5*ceil(ln(2048)), 2048) = 40
constexpr int UG = 8;   // u's per pv block
constexpr int NCH = 8;  // L-chunks per (b,h) in scores kernel (256 rows each)
constexpr int LPB = 16; // l's per block in compute_M v2
constexpr int RCH = 8;  // row chunks (256 rows each) in pv_partial

typedef float floatx4 __attribute__((ext_vector_type(4)));

// ---------------------------------------------------------------------------
// Kernel 0: out = v  (identity copy), nontemporal both ways.
// ---------------------------------------------------------------------------
__global__ void copy_v_kernel(const float* __restrict__ v, float* __restrict__ out, int n4) {
    int i = blockIdx.x * blockDim.x + threadIdx.x;
    int stride = gridDim.x * blockDim.x;
    const floatx4* src = reinterpret_cast<const floatx4*>(v);
    floatx4* dst = reinterpret_cast<floatx4*>(out);
    for (; i < n4; i += stride) {
        floatx4 x = __builtin_nontemporal_load(src + i);
        __builtin_nontemporal_store(x, dst + i);
    }
}

// ---------------------------------------------------------------------------
// Kernel 1 v2: M[b,h,l], 16 l's per block, XCD-affinity by bh.
// ---------------------------------------------------------------------------
template<int SKC>
__global__ void compute_M_kernel2(const float* __restrict__ q, const float* __restrict__ k,
                                  const int* __restrict__ sidx, float* __restrict__ M) {
    int blk = blockIdx.x;
    int xcd = blk & 7;
    int rest = blk >> 3;
    int bh_hi = rest & 7;
    int chunk = rest >> 3;            // 0 .. L/LPB-1
    int bh = bh_hi * 8 + xcd;         // bh%8 == blk%8
    int b = bh >> 4, h = bh & 15;

    int t = threadIdx.x;
    int lg = t >> 4;                  // local l 0..15
    int dg = t & 15;                  // 4-float group of D

    __shared__ int s_idx[LPB * SKC];
    for (int i = t; i < LPB * SKC; i += 256)
        s_idx[i] = sidx[(size_t)(chunk * LPB) * SKC + i];
    __syncthreads();

    int l = chunk * LPB + lg;
    floatx4 qv = __builtin_nontemporal_load(
        reinterpret_cast<const floatx4*>(q + ((size_t)(b * L + l) * H + h) * D + dg * 4));

    float mx = -FLT_MAX;
    float sm = 0.f;
    #pragma unroll 4
    for (int s = 0; s < SKC; ++s) {
        int kidx = s_idx[lg * SKC + s];
        floatx4 kv = *reinterpret_cast<const floatx4*>(
            k + ((size_t)(b * L + kidx) * H + h) * D + dg * 4);
        float p = qv.x * kv.x + qv.y * kv.y + qv.z * kv.z + qv.w * kv.w;
        #pragma unroll
        for (int off = 8; off >= 1; off >>= 1) p += __shfl_xor(p, off, 16);
        mx = fmaxf(mx, p);
        sm += p;
    }
    if (dg == 0) {
        M[(size_t)bh * L + l] = mx - sm * (1.0f / (float)L);
    }
}

// Fallback for unexpected SK
__global__ void compute_M_kernel(const float* __restrict__ q, const float* __restrict__ k,
                                 const int* __restrict__ sidx, float* __restrict__ M, int SK) {
    int bl = blockIdx.x;
    int b = bl / L;
    int l = bl % L;
    int t = threadIdx.x;
    int h = t >> 4;
    int dg = t & 15;

    const float* qrow = q + ((size_t)(b * L + l)) * H * D + h * D + dg * 4;
    float4 qv = *reinterpret_cast<const float4*>(qrow);

    float mx = -FLT_MAX;
    float sm = 0.f;
    for (int s = 0; s < SK; ++s) {
        int kidx = sidx[l * SK + s];
        const float* krow = k + ((size_t)(b * L + kidx)) * H * D + h * D + dg * 4;
        float4 kv = *reinterpret_cast<const float4*>(krow);
        float p = qv.x * kv.x + qv.y * kv.y + qv.z * kv.z + qv.w * kv.w;
        #pragma unroll
        for (int off = 8; off >= 1; off >>= 1) p += __shfl_xor(p, off, 16);
        mx = fmaxf(mx, p);
        sm += p;
    }
    if (dg == 0) {
        M[((size_t)(b * H + h)) * L + l] = mx - sm * (1.0f / (float)L);
    }
}

// ---------------------------------------------------------------------------
// Kernel 2: exact top-U per (b,h), jax.lax.top_k tie-breaking.
// ---------------------------------------------------------------------------
__global__ void topk_kernel(const float* __restrict__ M, int* __restrict__ Mtop) {
    int bh = blockIdx.x;
    const float* m = M + (size_t)bh * L;
    __shared__ float vals[L];
    __shared__ float rv[4];
    __shared__ int ri[4];
    int t = threadIdx.x;

    for (int i = t; i < L; i += 256) vals[i] = m[i];
    __syncthreads();

    for (int u = 0; u < U; ++u) {
        float bv = -FLT_MAX;
        int bi = L;
        for (int i = t; i < L; i += 256) {
            float v = vals[i];
            if (v > bv || (v == bv && i < bi)) { bv = v; bi = i; }
        }
        #pragma unroll
        for (int off = 32; off >= 1; off >>= 1) {
            float ov = __shfl_xor(bv, off);
            int   oi = __shfl_xor(bi, off);
            if (ov > bv || (ov == bv && oi < bi)) { bv = ov; bi = oi; }
        }
        int w = t >> 6;
        if ((t & 63) == 0) { rv[w] = bv; ri[w] = bi; }
        __syncthreads();
        if (t == 0) {
            float fv = rv[0]; int fi = ri[0];
            #pragma unroll
            for (int j = 1; j < 4; ++j) {
                if (rv[j] > fv || (rv[j] == fv && ri[j] < fi)) { fv = rv[j]; fi = ri[j]; }
            }
            Mtop[bh * U + u] = fi;
            vals[fi] = -FLT_MAX;
        }
        __syncthreads();
    }
}

// ---------------------------------------------------------------------------
// Kernel 3a: scores. Block = (bh, L-chunk of 256). One thread per key row.
// ---------------------------------------------------------------------------
__global__ void scores_kernel(const float* __restrict__ q, const float* __restrict__ k,
                              const int* __restrict__ Mtop, float* __restrict__ sc) {
    int blk = blockIdx.x;
    int bh = blk >> 3;           // /NCH
    int ch = blk & (NCH - 1);
    int b = bh / H, h = bh % H;
    int t = threadIdx.x;

    __shared__ __align__(16) float qs[U][D];
    for (int i = t; i < U * D; i += 256) {
        int u = i >> 6, dd = i & 63;
        int qi = Mtop[bh * U + u];
        qs[u][dd] = q[((size_t)(b * L + qi)) * H * D + h * D + dd];
    }
    __syncthreads();

    int r = ch * 256 + t;
    const float4* krow = reinterpret_cast<const float4*>(k + ((size_t)(b * L + r)) * H * D + h * D);
    float4 kr[16];
    #pragma unroll
    for (int j = 0; j < 16; ++j) kr[j] = krow[j];

    float* scb = sc + (size_t)bh * U * L;
    for (int u = 0; u < U; ++u) {
        const float4* qrow = reinterpret_cast<const float4*>(qs[u]);
        float acc = 0.f;
        #pragma unroll
        for (int j = 0; j < 16; ++j) {
            float4 qv = qrow[j];
            acc += qv.x * kr[j].x + qv.y * kr[j].y + qv.z * kr[j].z + qv.w * kr[j].w;
        }
        scb[(size_t)u * L + r] = acc * 0.125f;
    }
}

// ---------------------------------------------------------------------------
// Kernel 3b: softmax over each sc row of L. Block per (bh,u). 8 vals/thread.
// ---------------------------------------------------------------------------
__global__ void softmax_kernel(float* __restrict__ sc) {
    int bhu = blockIdx.x;
    float* s = sc + (size_t)bhu * L;
    int t = threadIdx.x;
    __shared__ float redm[4];
    __shared__ float reds[4];

    float4 a = reinterpret_cast<const float4*>(s)[t];
    float4 c = reinterpret_cast<const float4*>(s)[t + 256];

    float m = fmaxf(fmaxf(fmaxf(a.x, a.y), fmaxf(a.z, a.w)),
                    fmaxf(fmaxf(c.x, c.y), fmaxf(c.z, c.w)));
    #pragma unroll
    for (int off = 32; off >= 1; off >>= 1) m = fmaxf(m, __shfl_xor(m, off));
    if ((t & 63) == 0) redm[t >> 6] = m;
    __syncthreads();
    float gm = fmaxf(fmaxf(redm[0], redm[1]), fmaxf(redm[2], redm[3]));

    a.x = __expf(a.x - gm); a.y = __expf(a.y - gm);
    a.z = __expf(a.z - gm); a.w = __expf(a.w - gm);
    c.x = __expf(c.x - gm); c.y = __expf(c.y - gm);
    c.z = __expf(c.z - gm); c.w = __expf(c.w - gm);
    float ls = a.x + a.y + a.z + a.w + c.x + c.y + c.z + c.w;
    #pragma unroll
    for (int off = 32; off >= 1; off >>= 1) ls += __shfl_xor(ls, off);
    if ((t & 63) == 0) reds[t >> 6] = ls;
    __syncthreads();
    float inv = 1.0f / (reds[0] + reds[1] + reds[2] + reds[3]);

    a.x *= inv; a.y *= inv; a.z *= inv; a.w *= inv;
    c.x *= inv; c.y *= inv; c.z *= inv; c.w *= inv;
    reinterpret_cast<float4*>(s)[t] = a;
    reinterpret_cast<float4*>(s)[t + 256] = c;
}

// ---------------------------------------------------------------------------
// Kernel 3c v2 stage 1: partial PV. Block = (bh, ug, rch) = 2560 blocks.
// Each block: 256 rows x 8 u's. Wave w covers rows rch*256 + w*64 .. +63.
// Writes partial[bh][u][rch][64].
// ---------------------------------------------------------------------------
__global__ void pv_partial_kernel(const float* __restrict__ v, const float* __restrict__ p,
                                  float* __restrict__ partial) {
    int blk = blockIdx.x;
    // swizzle: bh%8 == blk%8 (XCD affinity for v slices)
    int xcd = blk & 7;
    int rest = blk >> 3;          // 0..319
    int bh_hi = rest & 7;
    int rest2 = rest >> 3;        // 0..39
    int bh = bh_hi * 8 + xcd;
    int ug = rest2 >> 3;          // /RCH, 0..4
    int rch = rest2 & (RCH - 1);  // 0..7
    int b = bh / H, h = bh % H;
    int t = threadIdx.x;
    int d = t & 63;
    int w = t >> 6;

    const float* pb = p + ((size_t)bh * U + (size_t)ug * UG) * L;
    const float* vb = v + ((size_t)b * L * H + h) * D + d;

    float acc[UG];
    #pragma unroll
    for (int u = 0; u < UG; ++u) acc[u] = 0.f;

    int r0 = rch * 256 + w * 64;
    for (int rr = 0; rr < 64; rr += 2) {
        int r1 = r0 + rr;
        int r2 = r0 + rr + 1;
        float v1 = vb[(size_t)r1 * H * D];
        float v2 = vb[(size_t)r2 * H * D];
        #pragma unroll
        for (int u = 0; u < UG; ++u) {
            float p1 = pb[(size_t)u * L + r1];
            float p2 = pb[(size_t)u * L + r2];
            acc[u] = fmaf(p2, v2, fmaf(p1, v1, acc[u]));
        }
    }

    __shared__ float red[4][UG][64];
    #pragma unroll
    for (int u = 0; u < UG; ++u) red[w][u][d] = acc[u];
    __syncthreads();

    for (int i = t; i < UG * 64; i += 256) {
        int u = i >> 6, dd = i & 63;
        float s = red[0][u][dd] + red[1][u][dd] + red[2][u][dd] + red[3][u][dd];
        partial[(((size_t)bh * U + ug * UG + u) * RCH + rch) * 64 + dd] = s;
    }
}

// ---------------------------------------------------------------------------
// Kernel 3c v2 stage 2: reduce partials and scatter into out.
// One thread per (bh,u,d). Grid = B*H*U*64/256 = 640 blocks.
// ---------------------------------------------------------------------------
__global__ void pv_reduce_kernel(const float* __restrict__ partial, const int* __restrict__ Mtop,
                                 float* __restrict__ out) {
    int idx = blockIdx.x * 256 + threadIdx.x;   // 0 .. B*H*U*64-1
    int dd = idx & 63;
    int bhu = idx >> 6;                          // 0..2559
    int bh = bhu / U;
    int b = bh / H, h = bh % H;

    const float* pp = partial + (size_t)bhu * RCH * 64 + dd;
    float s = 0.f;
    #pragma unroll
    for (int c = 0; c < RCH; ++c) s += pp[c * 64];

    int qi = Mtop[bhu];
    out[((size_t)(b * L + qi) * H + h) * D + dd] = s;
}

// ---------------------------------------------------------------------------
// Old single-stage PV (fallback if partial buffer doesn't fit).
// ---------------------------------------------------------------------------
__global__ void pv_kernel(const float* __restrict__ v, const float* __restrict__ p,
                          const int* __restrict__ Mtop, float* __restrict__ out) {
    int blk = blockIdx.x;
    int xcd = blk & 7;
    int rest = blk >> 3;
    int bh_hi = rest & 7;
    int ug = rest >> 3;
    int bh = bh_hi * 8 + xcd;
    int b = bh / H, h = bh % H;
    int t = threadIdx.x;
    int d = t & 63;
    int w = t >> 6;

    const float* pb = p + ((size_t)bh * U + (size_t)ug * UG) * L;
    float acc[UG];
    #pragma unroll
    for (int u = 0; u < UG; ++u) acc[u] = 0.f;

    for (int r = w * 512; r < (w + 1) * 512; ++r) {
        float vv = v[((size_t)(b * L + r)) * H * D + h * D + d];
        #pragma unroll
        for (int u = 0; u < UG; ++u) acc[u] += pb[(size_t)u * L + r] * vv;
    }

    __shared__ float red[4][UG][64];
    #pragma unroll
    for (int u = 0; u < UG; ++u) red[w][u][d] = acc[u];
    __syncthreads();

    for (int i = t; i < UG * 64; i += 256) {
        int u = i >> 6, dd = i & 63;
        float s = red[0][u][dd] + red[1][u][dd] + red[2][u][dd] + red[3][u][dd];
        int qi = Mtop[bh * U + ug * UG + u];
        out[((size_t)(b * L + qi)) * H * D + h * D + dd] = s;
    }
}

// ---------------------------------------------------------------------------
// Fallback attention if workspace too small for the score buffer.
// ---------------------------------------------------------------------------
__global__ void attn_kernel_fallback(const float* __restrict__ q, const float* __restrict__ k,
                                     const float* __restrict__ v, const int* __restrict__ Mtop,
                                     float* __restrict__ out) {
    int blk = blockIdx.x;
    int bh = blk / U;
    int u = blk % U;
    int b = bh / H;
    int h = bh % H;
    int qi = Mtop[bh * U + u];

    __shared__ float sc[L];
    __shared__ float qs[D];
    __shared__ float red[4];
    __shared__ float ctx_s[4][D];

    int t = threadIdx.x;
    if (t < D) qs[t] = q[((size_t)(b * L + qi)) * H * D + h * D + t];
    __syncthreads();

    float lm = -FLT_MAX;
    for (int i = t; i < L; i += 256) {
        const float* krow = k + ((size_t)(b * L + i)) * H * D + h * D;
        float acc = 0.f;
        #pragma unroll
        for (int dd = 0; dd < D; ++dd) acc += qs[dd] * krow[dd];
        acc *= 0.125f;
        sc[i] = acc;
        lm = fmaxf(lm, acc);
    }
    #pragma unroll
    for (int off = 32; off >= 1; off >>= 1) lm = fmaxf(lm, __shfl_xor(lm, off));
    if ((t & 63) == 0) red[t >> 6] = lm;
    __syncthreads();
    float gm = fmaxf(fmaxf(red[0], red[1]), fmaxf(red[2], red[3]));

    float ls = 0.f;
    for (int i = t; i < L; i += 256) {
        float e = expf(sc[i] - gm);
        sc[i] = e;
        ls += e;
    }
    #pragma unroll
    for (int off = 32; off >= 1; off >>= 1) ls += __shfl_xor(ls, off);
    __syncthreads();
    if ((t & 63) == 0) red[t >> 6] = ls;
    __syncthreads();
    float inv = 1.0f / (red[0] + red[1] + red[2] + red[3]);

    int d = t & 63;
    int g = t >> 6;
    float acc = 0.f;
    for (int i = g; i < L; i += 4) {
        acc += sc[i] * v[((size_t)(b * L + i)) * H * D + h * D + d];
    }
    ctx_s[g][d] = acc;
    __syncthreads();
    if (g == 0) {
        float c = (ctx_s[0][d] + ctx_s[1][d] + ctx_s[2][d] + ctx_s[3][d]) * inv;
        out[((size_t)(b * L + qi)) * H * D + h * D + d] = c;
    }
}

// ---------------------------------------------------------------------------
extern "C" void kernel_launch(void* const* d_in, const int* in_sizes, int n_in,
                              void* d_out, int out_size, void* d_ws, size_t ws_size,
                              hipStream_t stream) {
    const float* q = (const float*)d_in[0];
    const float* k = (const float*)d_in[1];
    const float* v = (const float*)d_in[2];
    const int* sidx = (const int*)d_in[3];
    float* out = (float*)d_out;

    int SK = in_sizes[3] / L;  // sample_k (40 for this shape)

    // Workspace layout
    size_t offM = 0;                                        // B*H*L floats
    size_t offMtop = offM + (size_t)B * H * L * sizeof(float);
    size_t offSc = offMtop + (size_t)B * H * U * sizeof(int);
    offSc = (offSc + 255) & ~(size_t)255;
    size_t offPart = offSc + (size_t)B * H * U * L * sizeof(float);
    offPart = (offPart + 255) & ~(size_t)255;
    size_t needSc = offPart;                                // through sc
    size_t needAll = offPart + (size_t)B * H * U * RCH * 64 * sizeof(float);

    float* M = (float*)((char*)d_ws + offM);
    int* Mtop = (int*)((char*)d_ws + offMtop);
    float* sc = (float*)((char*)d_ws + offSc);
    float* partial = (float*)((char*)d_ws + offPart);

    int n4 = (B * L * H * D) / 4;
    copy_v_kernel<<<2048, 256, 0, stream>>>(v, out, n4);

    if (SK == 40) {
        compute_M_kernel2<40><<<B * H * (L / LPB), 256, 0, stream>>>(q, k, sidx, M);
    } else {
        compute_M_kernel<<<B * L, 256, 0, stream>>>(q, k, sidx, M, SK);
    }
    topk_kernel<<<B * H, 256, 0, stream>>>(M, Mtop);

    if (ws_size >= needSc) {
        scores_kernel<<<B * H * NCH, 256, 0, stream>>>(q, k, Mtop, sc);
        softmax_kernel<<<B * H * U, 256, 0, stream>>>(sc);
        if (ws_size >= needAll) {
            pv_partial_kernel<<<B * H * (U / UG) * RCH, 256, 0, stream>>>(v, sc, partial);
            pv_reduce_kernel<<<B * H * U * 64 / 256, 256, 0, stream>>>(partial, Mtop, out);
        } else {
            pv_kernel<<<B * H * (U / UG), 256, 0, stream>>>(v, sc, Mtop, out);
        }
    } else {
        attn_kernel_fallback<<<B * H * U, 256, 0, stream>>>(q, k, v, Mtop, out);
    }
}

// Round 5
// 268.980 us; speedup vs baseline: 2.4225x; 1.0278x over previous
//
#include <hip/hip_runtime.h>
#include <hip/hip_bf16.h>
#include <float.h>
#include <math.h>

// Problem constants (B, L, H, D fixed by the reference setup)
constexpr int B = 4;
constexpr int L = 2048;
constexpr int H = 16;
constexpr int D = 64;
constexpr int U = 40;   // u_top = min(5*ceil(ln(2048)), 2048) = 40
constexpr int UG = 8;   // u's per pv block
constexpr int NCH = 8;  // L-chunks per (b,h) in scores kernel (256 rows each)
constexpr int LPB = 16; // l's per block in compute_M
constexpr int RCH = 8;  // row chunks (256 rows each) in pv_partial

constexpr int MBLK = B * H * (L / LPB);  // 8192 compute-M blocks
constexpr int CPBLK = 2048;              // copy blocks appended to same grid

typedef float floatx4 __attribute__((ext_vector_type(4)));

// ---------------------------------------------------------------------------
// Fused kernel: blocks [0,MBLK) compute M; blocks [MBLK, MBLK+CPBLK) copy v->out.
// M part: block = (bh XCD-affine, chunk of 16 l's). Wave handles one l at a
// time: lane = g*8 + dpart; sample s = iter*8 + g (5 iters * 8 groups = 40);
// each lane dots 8 elems (two float4 at dpart*16B and 128+dpart*16B -> every
// load instruction covers 8 full 128B lines). 3 shuffles per iter for the dot,
// 6 shuffles per l for the max/sum cross-sample reduce.
// ---------------------------------------------------------------------------
template<int SKC>
__global__ void fused_copy_M_kernel(const float* __restrict__ q, const float* __restrict__ k,
                                    const float* __restrict__ v, const int* __restrict__ sidx,
                                    float* __restrict__ out, float* __restrict__ M, int n4) {
    int blk = blockIdx.x;
    int t = threadIdx.x;

    if (blk >= MBLK) {
        // ---- copy part ----
        int i = (blk - MBLK) * 256 + t;
        int stride = CPBLK * 256;
        const floatx4* src = reinterpret_cast<const floatx4*>(v);
        floatx4* dst = reinterpret_cast<floatx4*>(out);
        for (; i < n4; i += stride) {
            floatx4 x = __builtin_nontemporal_load(src + i);
            __builtin_nontemporal_store(x, dst + i);
        }
        return;
    }

    // ---- compute-M part ----
    int xcd = blk & 7;
    int rest = blk >> 3;
    int bh_hi = rest & 7;
    int chunk = rest >> 3;            // 0 .. L/LPB-1
    int bh = bh_hi * 8 + xcd;         // bh%8 == blk%8 (XCD affinity)
    int b = bh >> 4, h = bh & 15;

    __shared__ int s_idx[LPB * SKC];
    for (int i = t; i < LPB * SKC; i += 256)
        s_idx[i] = sidx[(size_t)chunk * LPB * SKC + i];
    __syncthreads();

    int w = t >> 6;
    int lane = t & 63;
    int g = lane >> 3;      // sample group 0..7
    int dpart = lane & 7;   // 8-elem slice of D

    #pragma unroll
    for (int li = 0; li < 4; ++li) {
        int lg = w * 4 + li;
        int l = chunk * LPB + lg;

        const float* qrow = q + ((size_t)(b * L + l) * H + h) * D;
        floatx4 qa = *reinterpret_cast<const floatx4*>(qrow + dpart * 4);
        floatx4 qb = *reinterpret_cast<const floatx4*>(qrow + 32 + dpart * 4);

        int sid[SKC / 8];
        #pragma unroll
        for (int i = 0; i < SKC / 8; ++i) sid[i] = s_idx[lg * SKC + i * 8 + g];

        float mx = -FLT_MAX;
        float sm = 0.f;
        #pragma unroll
        for (int i = 0; i < SKC / 8; ++i) {
            const float* krow = k + ((size_t)(b * L + sid[i]) * H + h) * D;
            floatx4 ka = *reinterpret_cast<const floatx4*>(krow + dpart * 4);
            floatx4 kb = *reinterpret_cast<const floatx4*>(krow + 32 + dpart * 4);
            float p = qa.x * ka.x + qa.y * ka.y + qa.z * ka.z + qa.w * ka.w
                    + qb.x * kb.x + qb.y * kb.y + qb.z * kb.z + qb.w * kb.w;
            p += __shfl_xor(p, 1);
            p += __shfl_xor(p, 2);
            p += __shfl_xor(p, 4);
            mx = fmaxf(mx, p);
            sm += p;
        }
        // cross-sample-group reduce (groups are lanes 8 apart)
        #pragma unroll
        for (int off = 8; off <= 32; off <<= 1) {
            mx = fmaxf(mx, __shfl_xor(mx, off));
            sm += __shfl_xor(sm, off);
        }
        if (lane == 0) M[(size_t)bh * L + l] = mx - sm * (1.0f / (float)L);
    }
}

// Standalone copy (fallback path)
__global__ void copy_v_kernel(const float* __restrict__ v, float* __restrict__ out, int n4) {
    int i = blockIdx.x * blockDim.x + threadIdx.x;
    int stride = gridDim.x * blockDim.x;
    const floatx4* src = reinterpret_cast<const floatx4*>(v);
    floatx4* dst = reinterpret_cast<floatx4*>(out);
    for (; i < n4; i += stride) {
        floatx4 x = __builtin_nontemporal_load(src + i);
        __builtin_nontemporal_store(x, dst + i);
    }
}

// Fallback M for unexpected SK
__global__ void compute_M_kernel(const float* __restrict__ q, const float* __restrict__ k,
                                 const int* __restrict__ sidx, float* __restrict__ M, int SK) {
    int bl = blockIdx.x;
    int b = bl / L;
    int l = bl % L;
    int t = threadIdx.x;
    int h = t >> 4;
    int dg = t & 15;

    const float* qrow = q + ((size_t)(b * L + l)) * H * D + h * D + dg * 4;
    float4 qv = *reinterpret_cast<const float4*>(qrow);

    float mx = -FLT_MAX;
    float sm = 0.f;
    for (int s = 0; s < SK; ++s) {
        int kidx = sidx[l * SK + s];
        const float* krow = k + ((size_t)(b * L + kidx)) * H * D + h * D + dg * 4;
        float4 kv = *reinterpret_cast<const float4*>(krow);
        float p = qv.x * kv.x + qv.y * kv.y + qv.z * kv.z + qv.w * kv.w;
        #pragma unroll
        for (int off = 8; off >= 1; off >>= 1) p += __shfl_xor(p, off, 16);
        mx = fmaxf(mx, p);
        sm += p;
    }
    if (dg == 0) {
        M[((size_t)(b * H + h)) * L + l] = mx - sm * (1.0f / (float)L);
    }
}

// ---------------------------------------------------------------------------
// Kernel 2: exact top-U per (b,h), jax.lax.top_k tie-breaking.
// ---------------------------------------------------------------------------
__global__ void topk_kernel(const float* __restrict__ M, int* __restrict__ Mtop) {
    int bh = blockIdx.x;
    const float* m = M + (size_t)bh * L;
    __shared__ float vals[L];
    __shared__ float rv[4];
    __shared__ int ri[4];
    int t = threadIdx.x;

    for (int i = t; i < L; i += 256) vals[i] = m[i];
    __syncthreads();

    for (int u = 0; u < U; ++u) {
        float bv = -FLT_MAX;
        int bi = L;
        for (int i = t; i < L; i += 256) {
            float v = vals[i];
            if (v > bv || (v == bv && i < bi)) { bv = v; bi = i; }
        }
        #pragma unroll
        for (int off = 32; off >= 1; off >>= 1) {
            float ov = __shfl_xor(bv, off);
            int   oi = __shfl_xor(bi, off);
            if (ov > bv || (ov == bv && oi < bi)) { bv = ov; bi = oi; }
        }
        int w = t >> 6;
        if ((t & 63) == 0) { rv[w] = bv; ri[w] = bi; }
        __syncthreads();
        if (t == 0) {
            float fv = rv[0]; int fi = ri[0];
            #pragma unroll
            for (int j = 1; j < 4; ++j) {
                if (rv[j] > fv || (rv[j] == fv && ri[j] < fi)) { fv = rv[j]; fi = ri[j]; }
            }
            Mtop[bh * U + u] = fi;
            vals[fi] = -FLT_MAX;
        }
        __syncthreads();
    }
}

// ---------------------------------------------------------------------------
// Kernel 3a: scores. Block = (bh, L-chunk of 256). One thread per key row.
// ---------------------------------------------------------------------------
__global__ void scores_kernel(const float* __restrict__ q, const float* __restrict__ k,
                              const int* __restrict__ Mtop, float* __restrict__ sc) {
    int blk = blockIdx.x;
    int bh = blk >> 3;           // /NCH
    int ch = blk & (NCH - 1);
    int b = bh / H, h = bh % H;
    int t = threadIdx.x;

    __shared__ __align__(16) float qs[U][D];
    for (int i = t; i < U * D; i += 256) {
        int u = i >> 6, dd = i & 63;
        int qi = Mtop[bh * U + u];
        qs[u][dd] = q[((size_t)(b * L + qi)) * H * D + h * D + dd];
    }
    __syncthreads();

    int r = ch * 256 + t;
    const float4* krow = reinterpret_cast<const float4*>(k + ((size_t)(b * L + r)) * H * D + h * D);
    float4 kr[16];
    #pragma unroll
    for (int j = 0; j < 16; ++j) kr[j] = krow[j];

    float* scb = sc + (size_t)bh * U * L;
    for (int u = 0; u < U; ++u) {
        const float4* qrow = reinterpret_cast<const float4*>(qs[u]);
        float acc = 0.f;
        #pragma unroll
        for (int j = 0; j < 16; ++j) {
            float4 qv = qrow[j];
            acc += qv.x * kr[j].x + qv.y * kr[j].y + qv.z * kr[j].z + qv.w * kr[j].w;
        }
        scb[(size_t)u * L + r] = acc * 0.125f;
    }
}

// ---------------------------------------------------------------------------
// Kernel 3b: softmax over each sc row of L. Block per (bh,u). 8 vals/thread.
// ---------------------------------------------------------------------------
__global__ void softmax_kernel(float* __restrict__ sc) {
    int bhu = blockIdx.x;
    float* s = sc + (size_t)bhu * L;
    int t = threadIdx.x;
    __shared__ float redm[4];
    __shared__ float reds[4];

    float4 a = reinterpret_cast<const float4*>(s)[t];
    float4 c = reinterpret_cast<const float4*>(s)[t + 256];

    float m = fmaxf(fmaxf(fmaxf(a.x, a.y), fmaxf(a.z, a.w)),
                    fmaxf(fmaxf(c.x, c.y), fmaxf(c.z, c.w)));
    #pragma unroll
    for (int off = 32; off >= 1; off >>= 1) m = fmaxf(m, __shfl_xor(m, off));
    if ((t & 63) == 0) redm[t >> 6] = m;
    __syncthreads();
    float gm = fmaxf(fmaxf(redm[0], redm[1]), fmaxf(redm[2], redm[3]));

    a.x = __expf(a.x - gm); a.y = __expf(a.y - gm);
    a.z = __expf(a.z - gm); a.w = __expf(a.w - gm);
    c.x = __expf(c.x - gm); c.y = __expf(c.y - gm);
    c.z = __expf(c.z - gm); c.w = __expf(c.w - gm);
    float ls = a.x + a.y + a.z + a.w + c.x + c.y + c.z + c.w;
    #pragma unroll
    for (int off = 32; off >= 1; off >>= 1) ls += __shfl_xor(ls, off);
    if ((t & 63) == 0) reds[t >> 6] = ls;
    __syncthreads();
    float inv = 1.0f / (reds[0] + reds[1] + reds[2] + reds[3]);

    a.x *= inv; a.y *= inv; a.z *= inv; a.w *= inv;
    c.x *= inv; c.y *= inv; c.z *= inv; c.w *= inv;
    reinterpret_cast<float4*>(s)[t] = a;
    reinterpret_cast<float4*>(s)[t + 256] = c;
}

// ---------------------------------------------------------------------------
// Kernel 3c stage 1: partial PV. Block = (bh, ug, rch) = 2560 blocks.
// ---------------------------------------------------------------------------
__global__ void pv_partial_kernel(const float* __restrict__ v, const float* __restrict__ p,
                                  float* __restrict__ partial) {
    int blk = blockIdx.x;
    int xcd = blk & 7;
    int rest = blk >> 3;          // 0..319
    int bh_hi = rest & 7;
    int rest2 = rest >> 3;        // 0..39
    int bh = bh_hi * 8 + xcd;
    int ug = rest2 >> 3;          // /RCH, 0..4
    int rch = rest2 & (RCH - 1);  // 0..7
    int b = bh / H, h = bh % H;
    int t = threadIdx.x;
    int d = t & 63;
    int w = t >> 6;

    const float* pb = p + ((size_t)bh * U + (size_t)ug * UG) * L;
    const float* vb = v + ((size_t)b * L * H + h) * D + d;

    float acc[UG];
    #pragma unroll
    for (int u = 0; u < UG; ++u) acc[u] = 0.f;

    int r0 = rch * 256 + w * 64;
    for (int rr = 0; rr < 64; rr += 2) {
        int r1 = r0 + rr;
        int r2 = r0 + rr + 1;
        float v1 = vb[(size_t)r1 * H * D];
        float v2 = vb[(size_t)r2 * H * D];
        #pragma unroll
        for (int u = 0; u < UG; ++u) {
            float p1 = pb[(size_t)u * L + r1];
            float p2 = pb[(size_t)u * L + r2];
            acc[u] = fmaf(p2, v2, fmaf(p1, v1, acc[u]));
        }
    }

    __shared__ float red[4][UG][64];
    #pragma unroll
    for (int u = 0; u < UG; ++u) red[w][u][d] = acc[u];
    __syncthreads();

    for (int i = t; i < UG * 64; i += 256) {
        int u = i >> 6, dd = i & 63;
        float s = red[0][u][dd] + red[1][u][dd] + red[2][u][dd] + red[3][u][dd];
        partial[(((size_t)bh * U + ug * UG + u) * RCH + rch) * 64 + dd] = s;
    }
}

// ---------------------------------------------------------------------------
// Kernel 3c stage 2: reduce partials and scatter into out.
// ---------------------------------------------------------------------------
__global__ void pv_reduce_kernel(const float* __restrict__ partial, const int* __restrict__ Mtop,
                                 float* __restrict__ out) {
    int idx = blockIdx.x * 256 + threadIdx.x;   // 0 .. B*H*U*64-1
    int dd = idx & 63;
    int bhu = idx >> 6;                          // 0..2559
    int bh = bhu / U;
    int b = bh / H, h = bh % H;

    const float* pp = partial + (size_t)bhu * RCH * 64 + dd;
    float s = 0.f;
    #pragma unroll
    for (int c = 0; c < RCH; ++c) s += pp[c * 64];

    int qi = Mtop[bhu];
    out[((size_t)(b * L + qi) * H + h) * D + dd] = s;
}

// ---------------------------------------------------------------------------
// Old single-stage PV (fallback if partial buffer doesn't fit).
// ---------------------------------------------------------------------------
__global__ void pv_kernel(const float* __restrict__ v, const float* __restrict__ p,
                          const int* __restrict__ Mtop, float* __restrict__ out) {
    int blk = blockIdx.x;
    int xcd = blk & 7;
    int rest = blk >> 3;
    int bh_hi = rest & 7;
    int ug = rest >> 3;
    int bh = bh_hi * 8 + xcd;
    int b = bh / H, h = bh % H;
    int t = threadIdx.x;
    int d = t & 63;
    int w = t >> 6;

    const float* pb = p + ((size_t)bh * U + (size_t)ug * UG) * L;
    float acc[UG];
    #pragma unroll
    for (int u = 0; u < UG; ++u) acc[u] = 0.f;

    for (int r = w * 512; r < (w + 1) * 512; ++r) {
        float vv = v[((size_t)(b * L + r)) * H * D + h * D + d];
        #pragma unroll
        for (int u = 0; u < UG; ++u) acc[u] += pb[(size_t)u * L + r] * vv;
    }

    __shared__ float red[4][UG][64];
    #pragma unroll
    for (int u = 0; u < UG; ++u) red[w][u][d] = acc[u];
    __syncthreads();

    for (int i = t; i < UG * 64; i += 256) {
        int u = i >> 6, dd = i & 63;
        float s = red[0][u][dd] + red[1][u][dd] + red[2][u][dd] + red[3][u][dd];
        int qi = Mtop[bh * U + ug * UG + u];
        out[((size_t)(b * L + qi)) * H * D + h * D + dd] = s;
    }
}

// ---------------------------------------------------------------------------
// Fallback attention if workspace too small for the score buffer.
// ---------------------------------------------------------------------------
__global__ void attn_kernel_fallback(const float* __restrict__ q, const float* __restrict__ k,
                                     const float* __restrict__ v, const int* __restrict__ Mtop,
                                     float* __restrict__ out) {
    int blk = blockIdx.x;
    int bh = blk / U;
    int u = blk % U;
    int b = bh / H;
    int h = bh % H;
    int qi = Mtop[bh * U + u];

    __shared__ float sc[L];
    __shared__ float qs[D];
    __shared__ float red[4];
    __shared__ float ctx_s[4][D];

    int t = threadIdx.x;
    if (t < D) qs[t] = q[((size_t)(b * L + qi)) * H * D + h * D + t];
    __syncthreads();

    float lm = -FLT_MAX;
    for (int i = t; i < L; i += 256) {
        const float* krow = k + ((size_t)(b * L + i)) * H * D + h * D;
        float acc = 0.f;
        #pragma unroll
        for (int dd = 0; dd < D; ++dd) acc += qs[dd] * krow[dd];
        acc *= 0.125f;
        sc[i] = acc;
        lm = fmaxf(lm, acc);
    }
    #pragma unroll
    for (int off = 32; off >= 1; off >>= 1) lm = fmaxf(lm, __shfl_xor(lm, off));
    if ((t & 63) == 0) red[t >> 6] = lm;
    __syncthreads();
    float gm = fmaxf(fmaxf(red[0], red[1]), fmaxf(red[2], red[3]));

    float ls = 0.f;
    for (int i = t; i < L; i += 256) {
        float e = expf(sc[i] - gm);
        sc[i] = e;
        ls += e;
    }
    #pragma unroll
    for (int off = 32; off >= 1; off >>= 1) ls += __shfl_xor(ls, off);
    __syncthreads();
    if ((t & 63) == 0) red[t >> 6] = ls;
    __syncthreads();
    float inv = 1.0f / (red[0] + red[1] + red[2] + red[3]);

    int d = t & 63;
    int g = t >> 6;
    float acc = 0.f;
    for (int i = g; i < L; i += 4) {
        acc += sc[i] * v[((size_t)(b * L + i)) * H * D + h * D + d];
    }
    ctx_s[g][d] = acc;
    __syncthreads();
    if (g == 0) {
        float c = (ctx_s[0][d] + ctx_s[1][d] + ctx_s[2][d] + ctx_s[3][d]) * inv;
        out[((size_t)(b * L + qi)) * H * D + h * D + d] = c;
    }
}

// ---------------------------------------------------------------------------
extern "C" void kernel_launch(void* const* d_in, const int* in_sizes, int n_in,
                              void* d_out, int out_size, void* d_ws, size_t ws_size,
                              hipStream_t stream) {
    const float* q = (const float*)d_in[0];
    const float* k = (const float*)d_in[1];
    const float* v = (const float*)d_in[2];
    const int* sidx = (const int*)d_in[3];
    float* out = (float*)d_out;

    int SK = in_sizes[3] / L;  // sample_k (40 for this shape)

    // Workspace layout
    size_t offM = 0;                                        // B*H*L floats
    size_t offMtop = offM + (size_t)B * H * L * sizeof(float);
    size_t offSc = offMtop + (size_t)B * H * U * sizeof(int);
    offSc = (offSc + 255) & ~(size_t)255;
    size_t offPart = offSc + (size_t)B * H * U * L * sizeof(float);
    offPart = (offPart + 255) & ~(size_t)255;
    size_t needSc = offPart;                                // through sc
    size_t needAll = offPart + (size_t)B * H * U * RCH * 64 * sizeof(float);

    float* M = (float*)((char*)d_ws + offM);
    int* Mtop = (int*)((char*)d_ws + offMtop);
    float* sc = (float*)((char*)d_ws + offSc);
    float* partial = (float*)((char*)d_ws + offPart);

    int n4 = (B * L * H * D) / 4;

    if (SK == 40) {
        fused_copy_M_kernel<40><<<MBLK + CPBLK, 256, 0, stream>>>(q, k, v, sidx, out, M, n4);
    } else {
        copy_v_kernel<<<2048, 256, 0, stream>>>(v, out, n4);
        compute_M_kernel<<<B * L, 256, 0, stream>>>(q, k, sidx, M, SK);
    }
    topk_kernel<<<B * H, 256, 0, stream>>>(M, Mtop);

    if (ws_size >= needSc) {
        scores_kernel<<<B * H * NCH, 256, 0, stream>>>(q, k, Mtop, sc);
        softmax_kernel<<<B * H * U, 256, 0, stream>>>(sc);
        if (ws_size >= needAll) {
            pv_partial_kernel<<<B * H * (U / UG) * RCH, 256, 0, stream>>>(v, sc, partial);
            pv_reduce_kernel<<<B * H * U * 64 / 256, 256, 0, stream>>>(partial, Mtop, out);
        } else {
            pv_kernel<<<B * H * (U / UG), 256, 0, stream>>>(v, sc, Mtop, out);
        }
    } else {
        attn_kernel_fallback<<<B * H * U, 256, 0, stream>>>(q, k, v, Mtop, out);
    }
}